// Round 4
// baseline (1880.420 us; speedup 1.0000x reference)
//
#include <hip/hip_runtime.h>
#include <math.h>

// VectorQuantizer: z (32,256,32,32) f32 -> flat (32768,256); codebook (8192,256) f32.
// d_out (float): [0,8388608) z_q_st ; [8388608] loss ; [8388609,8421377) indices-as-float.
//
// Tier-1 pipeline:
//   memset(pairCount) -> convert z,cb to bf16 -> dotmax_fast (codes-as-M MFMA,
//   double-buffered, top-2 dot per (row, 128-code group) -> records in d_out's
//   z_q region) -> select_pairs (thresholds + candidate-pair append) ->
//   rescore (1 candidate/lane, exact f32 chain, atomicMin pack(d,code)) ->
//   gather (reads rowBest) -> finalize loss.
// Exact arithmetic (sequential fmaf, dist = S - 2*dot, min-d-then-lowest-code)
// identical to rounds 1-3 (absmax 0.0 three times).

#define NROWS 32768
#define DIM   256
#define KCB   8192
#define NGRP  64          // 8192 codes / 128 per group
#define EPS_DOT 4e-4f     // prune margin on dot scale (worst-case bf16 err ~6e-5)

typedef __bf16 bf16_t;
typedef bf16_t bf16x4v __attribute__((ext_vector_type(4)));
typedef bf16_t bf16x8v __attribute__((ext_vector_type(8)));
typedef float  f32x4   __attribute__((ext_vector_type(4)));

#ifndef __has_builtin
#define __has_builtin(x) 0
#endif
#if __has_builtin(__builtin_amdgcn_global_load_lds)
#define HAS_GLD_LDS 1
#else
#define HAS_GLD_LDS 0
#endif

__device__ __forceinline__ void top2_insert(float& v1, int& c1, float& v2, int& c2,
                                            float w, int d) {
  if (w > v1 || (w == v1 && d < c1)) { v2 = v1; c2 = c1; v1 = w; c1 = d; }
  else if (w > v2 || (w == v2 && d < c2)) { v2 = w; c2 = d; }
}

__device__ __forceinline__ void top2_merge(float& v1, int& c1, float& v2, int& c2,
                                           float w1, int d1, float w2, int d2) {
  if (w1 > v1 || (w1 == v1 && d1 < c1)) {
    float nv2; int nc2;
    if (v1 > w2 || (v1 == w2 && c1 < d2)) { nv2 = v1; nc2 = c1; }
    else                                   { nv2 = w2; nc2 = d2; }
    v1 = w1; c1 = d1; v2 = nv2; c2 = nc2;
  } else if (w1 > v2 || (w1 == v2 && d1 < c2)) { v2 = w1; c2 = d1; }
}

// ---------------------------------------------------------------------------
// f32 -> bf16 convert.
// ---------------------------------------------------------------------------
__global__ __launch_bounds__(256) void vq_convert_kernel(
    const float* __restrict__ src, bf16_t* __restrict__ dst, int n4) {
  const int i = blockIdx.x * 256 + threadIdx.x;
  if (i < n4) {
    const float4 x = reinterpret_cast<const float4*>(src)[i];
    bf16x4v h;
    h[0] = (bf16_t)x.x; h[1] = (bf16_t)x.y; h[2] = (bf16_t)x.z; h[3] = (bf16_t)x.w;
    reinterpret_cast<bf16x4v*>(dst)[i] = h;
  }
}

// ---------------------------------------------------------------------------
// Tier-1 dotmax: codes on the M dimension (top-2 becomes register-local),
// double-buffered K pipeline with early STAGE issue.
// LDS tile layout (validated r3): 16B-chunk c of row r at slot c ^ (r&7).
// ---------------------------------------------------------------------------
__global__ __launch_bounds__(256, 2) void vq_dotmax_fast_kernel(
    const bf16_t* __restrict__ C, const bf16_t* __restrict__ Z,
    float4* __restrict__ records) {
  __shared__ __align__(16) char sC[2][16384];
  __shared__ __align__(16) char sZ[2][16384];
  __shared__ float4 red2[128][2];

  const int t = threadIdx.x;
  const int l = t & 63, w = t >> 6;
  const int wm = w >> 1, wn = w & 1;       // wm: code-half, wn: row-half
  const int l15 = l & 15, lhi = l >> 4;

  const int b  = blockIdx.x;
  const int wg = (b & 7) * 2048 + (b >> 3);   // XCD swizzle (16384 % 8 == 0)
  const int by = wg >> 6;                     // z-row tile 0..255
  const int bx = wg & 63;                     // code tile  0..63
  const long rb    = (long)by * 128;
  const long cbase = (long)bx * 128;

  const int rl0 = l >> 3;
  const int ch  = (l & 7) ^ rl0;              // pre-swizzled source chunk

  auto STAGE = [&](int buf, int kc) {
#pragma unroll
    for (int p = 0; p < 4; ++p) {
      const int rloc = (p * 4 + w) * 8 + rl0;
      const bf16_t* gc = C + (cbase + rloc) * 256 + kc * 64 + ch * 8;
      const bf16_t* gz = Z + (rb    + rloc) * 256 + kc * 64 + ch * 8;
      char* lc = sC[buf] + (p * 4 + w) * 1024;   // wave-uniform base
      char* lz = sZ[buf] + (p * 4 + w) * 1024;
#if HAS_GLD_LDS
      __builtin_amdgcn_global_load_lds(
          (const __attribute__((address_space(1))) void*)(uintptr_t)gc,
          (__attribute__((address_space(3))) void*)(uint32_t)(uintptr_t)lc,
          16, 0, 0);
      __builtin_amdgcn_global_load_lds(
          (const __attribute__((address_space(1))) void*)(uintptr_t)gz,
          (__attribute__((address_space(3))) void*)(uint32_t)(uintptr_t)lz,
          16, 0, 0);
#else
      *reinterpret_cast<uint4*>(lc + l * 16) = *reinterpret_cast<const uint4*>(gc);
      *reinterpret_cast<uint4*>(lz + l * 16) = *reinterpret_cast<const uint4*>(gz);
#endif
    }
  };

  f32x4 acc[4][4];
#pragma unroll
  for (int i = 0; i < 4; ++i)
#pragma unroll
    for (int j = 0; j < 4; ++j) acc[i][j] = (f32x4)0.0f;

  STAGE(0, 0);
  __syncthreads();

  for (int kc = 0; kc < 4; ++kc) {
    const int buf = kc & 1;
    if (kc < 3) STAGE(buf ^ 1, kc + 1);      // issue next-tile loads early
#pragma unroll
    for (int ks = 0; ks < 2; ++ks) {
      bf16x8v a[4], bz[4];
#pragma unroll
      for (int i = 0; i < 4; ++i) {
        const int r = wm * 64 + i * 16 + l15;           // code row
        a[i] = *reinterpret_cast<const bf16x8v*>(
            sC[buf] + r * 128 + ((ks * 64 + lhi * 16) ^ ((r & 7) << 4)));
        const int rr = wn * 64 + i * 16 + l15;          // z row
        bz[i] = *reinterpret_cast<const bf16x8v*>(
            sZ[buf] + rr * 128 + ((ks * 64 + lhi * 16) ^ ((rr & 7) << 4)));
      }
#pragma unroll
      for (int i = 0; i < 4; ++i)
#pragma unroll
        for (int j = 0; j < 4; ++j)
          acc[i][j] = __builtin_amdgcn_mfma_f32_16x16x32_bf16(a[i], bz[j], acc[i][j], 0, 0, 0);
    }
    __syncthreads();   // drains vmcnt too -> buf^1 complete for next iter
  }

  // Epilogue: C[code_local][zrow_local]; within frag col=l15 (z-row),
  // row=lhi*4+reg (code). Top-2 over codes: 16 in-lane inserts + 2 shfl merges.
  const int code0 = (int)cbase + wm * 64 + lhi * 4;
#pragma unroll
  for (int j = 0; j < 4; ++j) {
    float v1 = -__builtin_inff(), v2 = -__builtin_inff();
    int   c1 = 0x7fffffff,        c2 = 0x7fffffff;
#pragma unroll
    for (int i = 0; i < 4; ++i)
#pragma unroll
      for (int r = 0; r < 4; ++r)
        top2_insert(v1, c1, v2, c2, acc[i][j][r], code0 + i * 16 + r);
#pragma unroll
    for (int o = 16; o < 64; o <<= 1) {      // merge across lhi groups
      const float w1 = __shfl_xor(v1, o); const int d1 = __shfl_xor(c1, o);
      const float w2 = __shfl_xor(v2, o); const int d2 = __shfl_xor(c2, o);
      top2_merge(v1, c1, v2, c2, w1, d1, w2, d2);
    }
    if (lhi == 0)
      red2[wn * 64 + j * 16 + l15][wm] =
          make_float4(v1, __int_as_float(c1), v2, __int_as_float(c2));
  }
  __syncthreads();
  if (t < 128) {
    const float4 A4 = red2[t][0], B4 = red2[t][1];
    float v1 = A4.x, v2 = A4.z;
    int   c1 = __float_as_int(A4.y), c2 = __float_as_int(A4.w);
    top2_merge(v1, c1, v2, c2, B4.x, __float_as_int(B4.y), B4.z, __float_as_int(B4.w));
    records[(size_t)(rb + t) * NGRP + bx] =
        make_float4(v1, __int_as_float(c1), v2, __int_as_float(c2));
  }
}

// ---------------------------------------------------------------------------
// S1: per row (1 wave, 4 rows/block): threshold, ballots, exact S, candidate
// pair append (g1 singles; g2 groups expanded to all 128 codes). Overflow ->
// inline exact rescore (never expected). pair = row<<13 | code.
// ---------------------------------------------------------------------------
__global__ __launch_bounds__(256) void vq_select_pairs_kernel(
    const float* __restrict__ z, const float* __restrict__ cb,
    const float4* __restrict__ records, float* __restrict__ rowS,
    unsigned long long* __restrict__ rowBest, unsigned* __restrict__ pairs,
    unsigned* __restrict__ pairCount, unsigned cap) {
  __shared__ float sZ[4][DIM];
  const int t = threadIdx.x;
  const int l = t & 63, v = t >> 6;
  const int row = blockIdx.x * 4 + v;

  const float4 rec = records[(size_t)row * NGRP + l];
  const float m1 = rec.x, m2 = rec.z;
  const int   i1 = __float_as_int(rec.y);

  const float4 zv = *reinterpret_cast<const float4*>(&z[(size_t)row * DIM + l * 4]);
  *reinterpret_cast<float4*>(&sZ[v][l * 4]) = zv;

  float M = m1;
#pragma unroll
  for (int o = 1; o < 64; o <<= 1) M = fmaxf(M, __shfl_xor(M, o));
  const float thr = M - EPS_DOT;
  __syncthreads();

  float S = 0.0f;                    // exact sequential S (validated r1-r3)
  for (int d = 0; d < DIM; ++d) S = fmaf(sZ[v][d], sZ[v][d], S);

  const bool in2 = (m2 >= thr);
  const bool in1 = (m1 >= thr) && !in2;
  const unsigned long long g1m = __ballot(in1);
  const unsigned long long g2m = __ballot(in2);
  const int n1 = __popcll(g1m), n2 = __popcll(g2m);
  const unsigned total = (unsigned)n1 + (unsigned)n2 * 128u;

  unsigned base = 0;
  if (l == 0) base = atomicAdd(pairCount, total);
  base = (unsigned)__shfl((int)base, 0);

  if (base + total <= cap) {
    if (l == 0) { rowS[row] = S; rowBest[row] = ~0ull; }
    if (in1) {
      const unsigned rank = (unsigned)__popcll(g1m & ((1ull << l) - 1ull));
      pairs[base + rank] = ((unsigned)row << 13) | (unsigned)i1;
    }
    unsigned o = base + (unsigned)n1;
    unsigned long long mm = g2m;
    while (mm) {
      const int g = __builtin_ctzll(mm); mm &= mm - 1;
      pairs[o + l]      = ((unsigned)row << 13) | (unsigned)(g * 128 + l);
      pairs[o + 64 + l] = ((unsigned)row << 13) | (unsigned)(g * 128 + 64 + l);
      o += 128;
    }
  } else {
    // overflow fallback: inline exact rescore (r3 select2 logic)
    float bd = __builtin_inff();
    int   bi = 0x7fffffff;
    unsigned long long mm = g1m;
    while (mm) {
      const int g = __builtin_ctzll(mm); mm &= mm - 1;
      const int c = __shfl(i1, g);
      const float* crow = &cb[(size_t)c * DIM];
      float a = 0.0f;
      for (int d = 0; d < DIM; ++d) a = fmaf(sZ[v][d], crow[d], a);
      const float dist = S - 2.0f * a;
      if (dist < bd || (dist == bd && c < bi)) { bd = dist; bi = c; }
    }
    mm = g2m;
    while (mm) {
      const int g = __builtin_ctzll(mm); mm &= mm - 1;
#pragma unroll
      for (int half = 0; half < 2; ++half) {
        const int c = g * 128 + half * 64 + l;
        const float* crow = &cb[(size_t)c * DIM];
        float a = 0.0f;
        for (int d = 0; d < DIM; ++d) a = fmaf(sZ[v][d], crow[d], a);
        const float dist = S - 2.0f * a;
        if (dist < bd || (dist == bd && c < bi)) { bd = dist; bi = c; }
      }
    }
#pragma unroll
    for (int o = 1; o < 64; o <<= 1) {
      const float ov = __shfl_xor(bd, o);
      const int   oi = __shfl_xor(bi, o);
      if (ov < bd || (ov == bd && oi < bi)) { bd = ov; bi = oi; }
    }
    if (l == 0) {
      rowS[row] = S;
      rowBest[row] = ((unsigned long long)__float_as_uint(bd) << 32) | (unsigned)bi;
    }
  }
}

// ---------------------------------------------------------------------------
// S2: one candidate per lane; exact sequential-fmaf chain; atomicMin of
// pack(d_bits, code) == min-d then lowest-code (reference semantics).
// ---------------------------------------------------------------------------
__global__ __launch_bounds__(256) void vq_rescore_kernel(
    const float* __restrict__ z, const float* __restrict__ cb,
    const unsigned* __restrict__ pairs, const unsigned* __restrict__ pairCount,
    const float* __restrict__ rowS, unsigned long long* __restrict__ rowBest,
    unsigned cap) {
  unsigned cnt = *pairCount;
  if (cnt > cap) cnt = cap;
  const unsigned stride = gridDim.x * 256;
  for (unsigned i = blockIdx.x * 256 + threadIdx.x; i < cnt; i += stride) {
    const unsigned pr = pairs[i];
    const unsigned row = pr >> 13;
    if (row >= (unsigned)NROWS) continue;     // stale/poison slot guard
    const unsigned code = pr & 8191u;
    const float* zr = &z[(size_t)row * DIM];
    const float* cr = &cb[(size_t)code * DIM];
    float a = 0.0f;
    for (int d = 0; d < DIM; d += 4) {        // float4 loads, same fmaf order
      const float4 zv = *reinterpret_cast<const float4*>(&zr[d]);
      const float4 cv = *reinterpret_cast<const float4*>(&cr[d]);
      a = fmaf(zv.x, cv.x, a); a = fmaf(zv.y, cv.y, a);
      a = fmaf(zv.z, cv.z, a); a = fmaf(zv.w, cv.w, a);
    }
    const float dist = rowS[row] - 2.0f * a;
    atomicMin(&rowBest[row],
              ((unsigned long long)__float_as_uint(dist) << 32) | (unsigned long long)code);
  }
}

// ---------------------------------------------------------------------------
// Gather (tier 1): index from rowBest low word; writes z_q_st, idxf, partials.
// ---------------------------------------------------------------------------
__global__ __launch_bounds__(256) void vq_gather_best_kernel(
    const float* __restrict__ z, const float* __restrict__ cb,
    const unsigned long long* __restrict__ rowBest, float* __restrict__ zq_out,
    float* __restrict__ idxf_out, double* __restrict__ partials) {
  const int t = threadIdx.x;
  const size_t g = (size_t)blockIdx.x * 256 + t;
  const int row = (int)(g >> 6);
  const int p   = (int)(g & 63);
  const int k   = (int)(unsigned)(rowBest[row] & 0xffffffffull);
  if (p == 0) idxf_out[row] = (float)k;

  const float4 zv = *reinterpret_cast<const float4*>(&z[g * 4]);
  const float4 ev = *reinterpret_cast<const float4*>(&cb[(size_t)k * DIM + (p << 2)]);

  float4 d4, o;
  d4.x = ev.x - zv.x; d4.y = ev.y - zv.y; d4.z = ev.z - zv.z; d4.w = ev.w - zv.w;
  o.x = zv.x + d4.x;  o.y = zv.y + d4.y;  o.z = zv.z + d4.z;  o.w = zv.w + d4.w;
  *reinterpret_cast<float4*>(&zq_out[g * 4]) = o;

  float s = d4.x * d4.x + d4.y * d4.y + d4.z * d4.z + d4.w * d4.w;
#pragma unroll
  for (int off = 32; off > 0; off >>= 1) s += __shfl_down(s, off);

  __shared__ float wsum[4];
  if ((t & 63) == 0) wsum[t >> 6] = s;
  __syncthreads();
  if (t == 0)
    partials[blockIdx.x] = (double)(wsum[0] + wsum[1] + wsum[2] + wsum[3]);
}

__global__ __launch_bounds__(256) void vq_finalize_kernel(
    const double* __restrict__ partials, float* __restrict__ loss_out) {
  __shared__ double sh[256];
  const int t = threadIdx.x;
  double s = 0.0;
  for (int i = t; i < 8192; i += 256) s += partials[i];
  sh[t] = s;
  __syncthreads();
  for (int stride = 128; stride > 0; stride >>= 1) {
    if (t < stride) sh[t] += sh[t + stride];
    __syncthreads();
  }
  if (t == 0) loss_out[0] = (float)(1.25 * sh[0] / 8388608.0);
}

// ===========================================================================
// Fallback tier (ws too small): r3 pipeline verbatim (validated).
// ===========================================================================
__global__ __launch_bounds__(256, 2) void vq_dotmax_f32_kernel(
    const float* __restrict__ A, const float* __restrict__ B,
    float4* __restrict__ records) {
  __shared__ __align__(16) char sA[128 * 128];
  __shared__ __align__(16) char sB[128 * 128];
  __shared__ float4 red2[128][2];

  const int t = threadIdx.x;
  const int l = t & 63, w = t >> 6;
  const int wm = w >> 1, wn = w & 1;
  const int l15 = l & 15, lhi = l >> 4;

  const int b  = blockIdx.x;
  const int wg = (b & 7) * 2048 + (b >> 3);
  const int by = wg >> 6;
  const int bx = wg & 63;
  const long rb    = (long)by * 128;
  const long cbase = (long)bx * 128;

  f32x4 acc[4][4];
#pragma unroll
  for (int i = 0; i < 4; ++i)
#pragma unroll
    for (int j = 0; j < 4; ++j) acc[i][j] = (f32x4)0.0f;

  for (int kc = 0; kc < 4; ++kc) {
#pragma unroll
    for (int p = 0; p < 8; ++p) {
      const int q   = p * 256 + t;
      const int row = q >> 4;
      const int c4  = q & 15;
      const int dst = row * 128 + ((c4 * 8) ^ ((row & 7) << 4));
      const float4 va = *reinterpret_cast<const float4*>(
          &A[(rb + row) * DIM + kc * 64 + c4 * 4]);
      bf16x4v ha;
      ha[0] = (bf16_t)va.x; ha[1] = (bf16_t)va.y;
      ha[2] = (bf16_t)va.z; ha[3] = (bf16_t)va.w;
      *reinterpret_cast<bf16x4v*>(sA + dst) = ha;
      const float4 vb = *reinterpret_cast<const float4*>(
          &B[(cbase + row) * DIM + kc * 64 + c4 * 4]);
      bf16x4v hb;
      hb[0] = (bf16_t)vb.x; hb[1] = (bf16_t)vb.y;
      hb[2] = (bf16_t)vb.z; hb[3] = (bf16_t)vb.w;
      *reinterpret_cast<bf16x4v*>(sB + dst) = hb;
    }
    __syncthreads();
#pragma unroll
    for (int ks = 0; ks < 2; ++ks) {
      bf16x8v a[4], bb[4];
#pragma unroll
      for (int i = 0; i < 4; ++i) {
        const int r = wm * 64 + i * 16 + l15;
        a[i] = *reinterpret_cast<const bf16x8v*>(
            sA + r * 128 + ((ks * 64 + lhi * 16) ^ ((r & 7) << 4)));
        const int cr = wn * 64 + i * 16 + l15;
        bb[i] = *reinterpret_cast<const bf16x8v*>(
            sB + cr * 128 + ((ks * 64 + lhi * 16) ^ ((cr & 7) << 4)));
      }
#pragma unroll
      for (int i = 0; i < 4; ++i)
#pragma unroll
        for (int j = 0; j < 4; ++j)
          acc[i][j] = __builtin_amdgcn_mfma_f32_16x16x32_bf16(a[i], bb[j], acc[i][j], 0, 0, 0);
    }
    __syncthreads();
  }

#pragma unroll
  for (int i = 0; i < 4; ++i) {
#pragma unroll
    for (int r = 0; r < 4; ++r) {
      float v1 = acc[i][0][r];
      int   c1 = (int)cbase + wn * 64 + l15;
      float v2; int c2;
      {
        const float d = acc[i][1][r];
        const int  cc = (int)cbase + wn * 64 + 16 + l15;
        if (d > v1) { v2 = v1; c2 = c1; v1 = d; c1 = cc; }
        else        { v2 = d;  c2 = cc; }
      }
#pragma unroll
      for (int j = 2; j < 4; ++j) {
        const float d = acc[i][j][r];
        const int  cc = (int)cbase + wn * 64 + j * 16 + l15;
        if (d > v1)      { v2 = v1; c2 = c1; v1 = d; c1 = cc; }
        else if (d > v2) { v2 = d;  c2 = cc; }
      }
#pragma unroll
      for (int o = 1; o < 16; o <<= 1) {
        const float b1 = __shfl_xor(v1, o); const int d1 = __shfl_xor(c1, o);
        const float b2 = __shfl_xor(v2, o); const int d2 = __shfl_xor(c2, o);
        if (b1 > v1) {
          const float nv2 = (v1 > b2) ? v1 : b2;
          const int   nc2 = (v1 > b2) ? c1 : d2;
          v2 = nv2; c2 = nc2; v1 = b1; c1 = d1;
        } else if (b1 > v2) { v2 = b1; c2 = d1; }
      }
      if (l15 == 0)
        red2[wm * 64 + i * 16 + lhi * 4 + r][wn] =
            make_float4(v1, __int_as_float(c1), v2, __int_as_float(c2));
    }
  }
  __syncthreads();
  if (t < 128) {
    const float4 A4 = red2[t][0], B4 = red2[t][1];
    float v1 = A4.x, v2 = A4.z;
    int   c1 = __float_as_int(A4.y), c2 = __float_as_int(A4.w);
    top2_merge(v1, c1, v2, c2, B4.x, __float_as_int(B4.y), B4.z, __float_as_int(B4.w));
    records[(size_t)(rb + t) * NGRP + bx] =
        make_float4(v1, __int_as_float(c1), v2, __int_as_float(c2));
  }
}

__global__ __launch_bounds__(256) void vq_select2_kernel(
    const float* __restrict__ z, const float* __restrict__ cb,
    const float4* __restrict__ records, int* __restrict__ idx_out,
    float* __restrict__ idxf_out) {
  __shared__ float sZ[4][DIM];
  const int t = threadIdx.x;
  const int l = t & 63, v = t >> 6;
  const int row = blockIdx.x * 4 + v;

  const float4 rec = records[(size_t)row * NGRP + l];
  const float m1v = rec.x, m2v = rec.z;
  const int   i1  = __float_as_int(rec.y);

  const float4 zv = *reinterpret_cast<const float4*>(&z[(size_t)row * DIM + l * 4]);
  *reinterpret_cast<float4*>(&sZ[v][l * 4]) = zv;

  float M = m1v;
#pragma unroll
  for (int o = 1; o < 64; o <<= 1) M = fmaxf(M, __shfl_xor(M, o));
  const float thr = M - EPS_DOT;
  __syncthreads();

  float S = 0.0f;
  for (int d = 0; d < DIM; ++d) S = fmaf(sZ[v][d], sZ[v][d], S);

  unsigned long long g2 = __ballot(m2v >= thr);
  unsigned long long g1 = __ballot(m1v >= thr) & ~g2;

  float bd = __builtin_inff();
  int   bi = 0x7fffffff;
  unsigned long long mm = g1;
  while (mm) {
    const int g = __builtin_ctzll(mm); mm &= mm - 1;
    const int c = __shfl(i1, g);
    const float* crow = &cb[(size_t)c * DIM];
    float a = 0.0f;
    for (int d = 0; d < DIM; ++d) a = fmaf(sZ[v][d], crow[d], a);
    const float dist = S - 2.0f * a;
    if (dist < bd || (dist == bd && c < bi)) { bd = dist; bi = c; }
  }
  mm = g2;
  while (mm) {
    const int g = __builtin_ctzll(mm); mm &= mm - 1;
#pragma unroll
    for (int half = 0; half < 2; ++half) {
      const int c = g * 128 + half * 64 + l;
      const float* crow = &cb[(size_t)c * DIM];
      float a = 0.0f;
      for (int d = 0; d < DIM; ++d) a = fmaf(sZ[v][d], crow[d], a);
      const float dist = S - 2.0f * a;
      if (dist < bd || (dist == bd && c < bi)) { bd = dist; bi = c; }
    }
  }
#pragma unroll
  for (int o = 1; o < 64; o <<= 1) {
    const float ov = __shfl_xor(bd, o);
    const int   oi = __shfl_xor(bi, o);
    if (ov < bd || (ov == bd && oi < bi)) { bd = ov; bi = oi; }
  }
  if (l == 0) { idx_out[row] = bi; idxf_out[row] = (float)bi; }
}

__global__ __launch_bounds__(256) void vq_gather_kernel(
    const float* __restrict__ z, const float* __restrict__ cb,
    const int* __restrict__ idx, float* __restrict__ zq_out,
    double* __restrict__ partials) {
  const int t = threadIdx.x;
  const size_t g = (size_t)blockIdx.x * 256 + t;
  const int row = (int)(g >> 6);
  const int p   = (int)(g & 63);
  const int k   = idx[row];

  const float4 zv = *reinterpret_cast<const float4*>(&z[g * 4]);
  const float4 ev = *reinterpret_cast<const float4*>(&cb[(size_t)k * DIM + (p << 2)]);

  float4 d4, o;
  d4.x = ev.x - zv.x; d4.y = ev.y - zv.y; d4.z = ev.z - zv.z; d4.w = ev.w - zv.w;
  o.x = zv.x + d4.x;  o.y = zv.y + d4.y;  o.z = zv.z + d4.z;  o.w = zv.w + d4.w;
  *reinterpret_cast<float4*>(&zq_out[g * 4]) = o;

  float s = d4.x * d4.x + d4.y * d4.y + d4.z * d4.z + d4.w * d4.w;
#pragma unroll
  for (int off = 32; off > 0; off >>= 1) s += __shfl_down(s, off);

  __shared__ float wsum[4];
  if ((t & 63) == 0) wsum[t >> 6] = s;
  __syncthreads();
  if (t == 0)
    partials[blockIdx.x] = (double)(wsum[0] + wsum[1] + wsum[2] + wsum[3]);
}

extern "C" void kernel_launch(void* const* d_in, const int* in_sizes, int n_in,
                              void* d_out, int out_size, void* d_ws, size_t ws_size,
                              hipStream_t stream) {
  const float* z  = (const float*)d_in[0];
  const float* cb = (const float*)d_in[1];
  float* out  = (float*)d_out;
  float* zq   = out;                  // 8388608
  float* loss = out + 8388608;        // 1
  float* idxf = out + 8388609;        // 32768

  float4* records = (float4*)d_out;   // z_q region doubles as records scratch

  const size_t zb_b   = (size_t)NROWS * DIM * 2;   // 16 MB
  const size_t cbb_b  = (size_t)KCB * DIM * 2;     //  4 MB
  const size_t rowS_b = (size_t)NROWS * 4;         // 128 KB
  const size_t best_b = (size_t)NROWS * 8;         // 256 KB
  const size_t par_b  = 8192 * 8;                  //  64 KB
  const size_t cnt_b  = 128;
  const size_t fixed  = zb_b + cbb_b + rowS_b + best_b + par_b + cnt_b;

  if (ws_size >= fixed + 262144) {
    char* p = (char*)d_ws;
    bf16_t* zb   = (bf16_t*)p;                 p += zb_b;
    bf16_t* cbb  = (bf16_t*)p;                 p += cbb_b;
    float*  rowS = (float*)p;                  p += rowS_b;
    unsigned long long* rowBest = (unsigned long long*)p; p += best_b;
    double* partials = (double*)p;             p += par_b;
    unsigned* pairCount = (unsigned*)p;        p += cnt_b;
    unsigned* pairs = (unsigned*)p;
    size_t capS = (ws_size - fixed) / 4;
    if (capS > 2097152) capS = 2097152;
    const unsigned cap = (unsigned)capS;

    hipMemsetAsync(pairCount, 0, 4, stream);
    vq_convert_kernel<<<8192, 256, 0, stream>>>(z, zb, NROWS * DIM / 4);
    vq_convert_kernel<<<2048, 256, 0, stream>>>(cb, cbb, KCB * DIM / 4);
    vq_dotmax_fast_kernel<<<16384, 256, 0, stream>>>(cbb, zb, records);
    vq_select_pairs_kernel<<<NROWS / 4, 256, 0, stream>>>(
        z, cb, records, rowS, rowBest, pairs, pairCount, cap);
    vq_rescore_kernel<<<1024, 256, 0, stream>>>(
        z, cb, pairs, pairCount, rowS, rowBest, cap);
    vq_gather_best_kernel<<<8192, 256, 0, stream>>>(
        z, cb, rowBest, zq, idxf, partials);
    vq_finalize_kernel<<<1, 256, 0, stream>>>(partials, loss);
  } else {
    int*    idx      = (int*)d_ws;
    double* partials = (double*)((char*)d_ws + (size_t)NROWS * 4);
    vq_dotmax_f32_kernel<<<16384, 256, 0, stream>>>(z, cb, records);
    vq_select2_kernel<<<NROWS / 4, 256, 0, stream>>>(z, cb, records, idx, idxf);
    vq_gather_kernel<<<8192, 256, 0, stream>>>(z, cb, idx, zq, partials);
    vq_finalize_kernel<<<1, 256, 0, stream>>>(partials, loss);
  }
}

// Round 7
// 596.603 us; speedup vs baseline: 3.1519x; 3.1519x over previous
//
#include <hip/hip_runtime.h>
#include <math.h>

// VectorQuantizer: z (32,256,32,32) f32 -> flat (32768,256); codebook (8192,256) f32.
// d_out (float): [0,8388608) z_q_st ; [8388608] loss ; [8388609,8421377) indices-as-float.
//
// Tier-1: convert z,cb -> bf16; dotmax3 (256x128-tile bf16 MFMA, single-buffer
// r3 structure, codes-as-M, TOP-3 dot per (row, 128-code group) -> 16B records
// in d_out's z_q region); select3 (broadcast-rescore c1/c2, full scan only if
// v3 >= thr); gather + loss. Rescore arithmetic (sequential fmaf, dist =
// S - 2*dot, min-then-lowest-code) is byte-identical to rounds 1-4 (absmax 0.0).
//
// (2nd resubmission: rounds 5 and 6 both died at infrastructure level --
// container bring-up / GPU acquisition -- with no kernel verdict.)

#define NROWS 32768
#define DIM   256
#define KCB   8192
#define NGRP  64          // 8192 codes / 128 per group
#define EPS_DOT 4e-4f     // prune margin on dot scale (worst-case bf16 err ~5e-5)

typedef __bf16 bf16_t;
typedef bf16_t bf16x4v __attribute__((ext_vector_type(4)));
typedef bf16_t bf16x8v __attribute__((ext_vector_type(8)));
typedef float  f32x4   __attribute__((ext_vector_type(4)));

#ifndef __has_builtin
#define __has_builtin(x) 0
#endif
#if __has_builtin(__builtin_amdgcn_global_load_lds)
#define HAS_GLD_LDS 1
#else
#define HAS_GLD_LDS 0
#endif

// top-3 insert: (v1,c1,v2,c2,v3) <- value w with code d (codes kept for top-2
// only; slot-3 is value-only and triggers a full-group scan when >= thr).
__device__ __forceinline__ void t3_ins(float& v1, unsigned& c1, float& v2,
                                       unsigned& c2, float& v3, float w, unsigned d) {
  if (w > v1)      { v3 = v2; v2 = v1; c2 = c1; v1 = w; c1 = d; }
  else if (w > v2) { v3 = v2; v2 = w;  c2 = d; }
  else if (w > v3) { v3 = w; }
}

__device__ __forceinline__ void top2_merge(float& v1, int& c1, float& v2, int& c2,
                                           float w1, int d1, float w2, int d2) {
  if (w1 > v1 || (w1 == v1 && d1 < c1)) {
    float nv2; int nc2;
    if (v1 > w2 || (v1 == w2 && c1 < d2)) { nv2 = v1; nc2 = c1; }
    else                                   { nv2 = w2; nc2 = d2; }
    v1 = w1; c1 = d1; v2 = nv2; c2 = nc2;
  } else if (w1 > v2 || (w1 == v2 && d1 < c2)) { v2 = w1; c2 = d1; }
}

// ---------------------------------------------------------------------------
// f32 -> bf16 convert.
// ---------------------------------------------------------------------------
__global__ __launch_bounds__(256) void vq_convert_kernel(
    const float* __restrict__ src, bf16_t* __restrict__ dst, int n4) {
  const int i = blockIdx.x * 256 + threadIdx.x;
  if (i < n4) {
    const float4 x = reinterpret_cast<const float4*>(src)[i];
    bf16x4v h;
    h[0] = (bf16_t)x.x; h[1] = (bf16_t)x.y; h[2] = (bf16_t)x.z; h[3] = (bf16_t)x.w;
    reinterpret_cast<bf16x4v*>(dst)[i] = h;
  }
}

// ---------------------------------------------------------------------------
// dotmax3: 256 codes (M) x 128 z-rows (N) per block, 512 threads (8 waves as
// 4 code-quarters x 2 z-halves), BK=64, single LDS buffer, r3's 2-barrier
// loop (measured-good). LDS tile: 16B-chunk c of row r at byte r*128+(c^(r&7))*16
// (validated); staged via global_load_lds w/ pre-swizzled source (validated).
// Epilogue: per-lane register top-3 over codes + 2 shfl merges + LDS merge.
// records[row][group] = uint4{bits(v1), bits(v2), bits(v3), (c1<<16)|c2}.
// ---------------------------------------------------------------------------
__global__ __launch_bounds__(512, 4) void vq_dotmax3_kernel(
    const bf16_t* __restrict__ C, const bf16_t* __restrict__ Z,
    uint4* __restrict__ records) {
  __shared__ __align__(16) char sC[256 * 128];   // 32 KB (aliased by red after use)
  __shared__ __align__(16) char sZ[128 * 128];   // 16 KB

  const int t = threadIdx.x;
  const int l = t & 63, w = t >> 6;
  const int wm = w >> 1, wn = w & 1;             // code quarter / z half
  const int l15 = l & 15, lhi = l >> 4;

  const int b  = blockIdx.x;
  const int wg = (b & 7) * 1024 + (b >> 3);      // XCD swizzle (8192 % 8 == 0)
  const int by = wg >> 5;                        // z tile   0..255
  const int bx = wg & 31;                        // code tile 0..31
  const long rb    = (long)by * 128;
  const long cbase = (long)bx * 256;

  const int rl0 = l >> 3;
  const int ch  = (l & 7) ^ rl0;                 // pre-swizzled source chunk

  f32x4 acc[4][4];
#pragma unroll
  for (int i = 0; i < 4; ++i)
#pragma unroll
    for (int j = 0; j < 4; ++j) acc[i][j] = (f32x4)0.0f;

  for (int kc = 0; kc < 4; ++kc) {
    // ---- stage: wave w loads code rows [w*32,w*32+32), z rows [w*16,w*16+16)
#pragma unroll
    for (int p = 0; p < 4; ++p) {
      const bf16_t* gc = C + (cbase + w * 32 + p * 8 + rl0) * 256 + kc * 64 + ch * 8;
      char* lc = sC + (w * 32 + p * 8) * 128;    // wave-uniform base
#if HAS_GLD_LDS
      __builtin_amdgcn_global_load_lds(
          (const __attribute__((address_space(1))) void*)(uintptr_t)gc,
          (__attribute__((address_space(3))) void*)(uint32_t)(uintptr_t)lc,
          16, 0, 0);
#else
      *reinterpret_cast<uint4*>(lc + l * 16) = *reinterpret_cast<const uint4*>(gc);
#endif
    }
#pragma unroll
    for (int p = 0; p < 2; ++p) {
      const bf16_t* gz = Z + (rb + w * 16 + p * 8 + rl0) * 256 + kc * 64 + ch * 8;
      char* lz = sZ + (w * 16 + p * 8) * 128;
#if HAS_GLD_LDS
      __builtin_amdgcn_global_load_lds(
          (const __attribute__((address_space(1))) void*)(uintptr_t)gz,
          (__attribute__((address_space(3))) void*)(uint32_t)(uintptr_t)lz,
          16, 0, 0);
#else
      *reinterpret_cast<uint4*>(lz + l * 16) = *reinterpret_cast<const uint4*>(gz);
#endif
    }
    __syncthreads();
#pragma unroll
    for (int ks = 0; ks < 2; ++ks) {
      bf16x8v a[4], bz[4];
#pragma unroll
      for (int i = 0; i < 4; ++i) {
        const int r  = wm * 64 + i * 16 + l15;   // code row (A operand -> D row)
        a[i]  = *reinterpret_cast<const bf16x8v*>(
            sC + r * 128 + ((ks * 64 + lhi * 16) ^ ((r & 7) << 4)));
        const int rz = wn * 64 + i * 16 + l15;   // z row (B operand -> D col)
        bz[i] = *reinterpret_cast<const bf16x8v*>(
            sZ + rz * 128 + ((ks * 64 + lhi * 16) ^ ((rz & 7) << 4)));
      }
#pragma unroll
      for (int i = 0; i < 4; ++i)
#pragma unroll
        for (int j = 0; j < 4; ++j)
          acc[i][j] = __builtin_amdgcn_mfma_f32_16x16x32_bf16(a[i], bz[j], acc[i][j], 0, 0, 0);
    }
    __syncthreads();                             // protects single buffer + red alias
  }

  // ---- epilogue: D[code][zrow]; in-frag row (lhi*4+reg) = code, col (l15) = z
  // (operand-swapped form of the r1-validated mapping; r4 passed with it).
  uint4* red = reinterpret_cast<uint4*>(sC);     // [128 zloc][4 wm]
  const int code00 = (int)cbase + wm * 64 + lhi * 4;
#pragma unroll
  for (int j = 0; j < 4; ++j) {
    float v1 = -__builtin_inff(), v2 = -__builtin_inff(), v3 = -__builtin_inff();
    unsigned c1 = 0, c2 = 0;
#pragma unroll
    for (int i = 0; i < 4; ++i)
#pragma unroll
      for (int r = 0; r < 4; ++r)
        t3_ins(v1, c1, v2, c2, v3, acc[i][j][r], (unsigned)(code00 + i * 16 + r));
#pragma unroll
    for (int o = 16; o < 64; o <<= 1) {          // merge across lhi groups
      const float    w1 = __shfl_xor(v1, o);
      const unsigned d1 = (unsigned)__shfl_xor((int)c1, o);
      const float    w2 = __shfl_xor(v2, o);
      const unsigned d2 = (unsigned)__shfl_xor((int)c2, o);
      const float    w3 = __shfl_xor(v3, o);
      t3_ins(v1, c1, v2, c2, v3, w1, d1);
      t3_ins(v1, c1, v2, c2, v3, w2, d2);
      if (w3 > v3) v3 = w3;
    }
    if (l < 16) {
      uint4 rec;
      rec.x = __float_as_uint(v1); rec.y = __float_as_uint(v2);
      rec.z = __float_as_uint(v3); rec.w = (c1 << 16) | c2;
      red[(wn * 64 + j * 16 + l15) * 4 + wm] = rec;
    }
  }
  __syncthreads();
  if (t < 256) {                                 // zloc = t&127, group-half g = t>>7
    const int zloc = t & 127, g = t >> 7;
    const uint4 A = red[zloc * 4 + g * 2];
    const uint4 B = red[zloc * 4 + g * 2 + 1];
    float v1 = __uint_as_float(A.x), v2 = __uint_as_float(A.y), v3 = __uint_as_float(A.z);
    unsigned c1 = A.w >> 16, c2 = A.w & 0xffffu;
    t3_ins(v1, c1, v2, c2, v3, __uint_as_float(B.x), B.w >> 16);
    t3_ins(v1, c1, v2, c2, v3, __uint_as_float(B.y), B.w & 0xffffu);
    const float b3 = __uint_as_float(B.z);
    if (b3 > v3) v3 = b3;
    uint4 rec;
    rec.x = __float_as_uint(v1); rec.y = __float_as_uint(v2);
    rec.z = __float_as_uint(v3); rec.w = (c1 << 16) | c2;
    records[(size_t)(rb + zloc) * NGRP + (bx * 2 + g)] = rec;
  }
}

// ---------------------------------------------------------------------------
// select3: per row (1 wave, 4 rows/block). thr = max(v1) - eps. Broadcast
// rescores for c1 (v1>=thr) and c2 (v2>=thr); full 128-code scan only when
// v3 >= thr (rare; also covers c1,c2 of those groups). Exact f32 arithmetic.
// ---------------------------------------------------------------------------
__global__ __launch_bounds__(256) void vq_select3_kernel(
    const float* __restrict__ z, const float* __restrict__ cb,
    const uint4* __restrict__ records, int* __restrict__ idx_out,
    float* __restrict__ idxf_out) {
  __shared__ float sZf[4][DIM];
  const int t = threadIdx.x;
  const int l = t & 63, v = t >> 6;
  const int row = blockIdx.x * 4 + v;

  const uint4 rec = records[(size_t)row * NGRP + l];   // 1KB coalesced per row
  const float v1 = __uint_as_float(rec.x);
  const float v2 = __uint_as_float(rec.y);
  const float v3 = __uint_as_float(rec.z);
  const unsigned c1 = rec.w >> 16, c2 = rec.w & 0xffffu;

  const float4 zv = *reinterpret_cast<const float4*>(&z[(size_t)row * DIM + l * 4]);
  *reinterpret_cast<float4*>(&sZf[v][l * 4]) = zv;

  float M = v1;
#pragma unroll
  for (int o = 1; o < 64; o <<= 1) M = fmaxf(M, __shfl_xor(M, o));
  const float thr = M - EPS_DOT;
  __syncthreads();

  float S = 0.0f;                      // exact sequential S (validated r1-r4)
  for (int d = 0; d < DIM; ++d) S = fmaf(sZf[v][d], sZf[v][d], S);

  const unsigned long long m3 = __ballot(v3 >= thr);
  const unsigned long long m2 = __ballot(v2 >= thr) & ~m3;
  const unsigned long long m1 = __ballot(v1 >= thr) & ~m3;

  float bd = __builtin_inff();
  int   bi = 0x7fffffff;

  unsigned long long mm = m1;          // broadcast rescore of c1
  while (mm) {
    const int g = __builtin_ctzll(mm); mm &= mm - 1;
    const int c = __shfl((int)c1, g);
    const float* crow = &cb[(size_t)c * DIM];
    float a = 0.0f;
    for (int d = 0; d < DIM; ++d) a = fmaf(sZf[v][d], crow[d], a);
    const float dist = S - 2.0f * a;
    if (dist < bd || (dist == bd && c < bi)) { bd = dist; bi = c; }
  }
  mm = m2;                             // broadcast rescore of c2
  while (mm) {
    const int g = __builtin_ctzll(mm); mm &= mm - 1;
    const int c = __shfl((int)c2, g);
    const float* crow = &cb[(size_t)c * DIM];
    float a = 0.0f;
    for (int d = 0; d < DIM; ++d) a = fmaf(sZf[v][d], crow[d], a);
    const float dist = S - 2.0f * a;
    if (dist < bd || (dist == bd && c < bi)) { bd = dist; bi = c; }
  }
  mm = m3;                             // rare: full 128-code scan of the group
  while (mm) {
    const int g = __builtin_ctzll(mm); mm &= mm - 1;
#pragma unroll
    for (int half = 0; half < 2; ++half) {
      const int c = g * 128 + half * 64 + l;
      const float* crow = &cb[(size_t)c * DIM];
      float a = 0.0f;
      for (int d = 0; d < DIM; ++d) a = fmaf(sZf[v][d], crow[d], a);
      const float dist = S - 2.0f * a;
      if (dist < bd || (dist == bd && c < bi)) { bd = dist; bi = c; }
    }
  }
#pragma unroll
  for (int o = 1; o < 64; o <<= 1) {
    const float ov = __shfl_xor(bd, o);
    const int   oi = __shfl_xor(bi, o);
    if (ov < bd || (ov == bd && oi < bi)) { bd = ov; bi = oi; }
  }
  if (l == 0) { idx_out[row] = bi; idxf_out[row] = (float)bi; }
}

// ---------------------------------------------------------------------------
// Gather z_q, z_q_st = z + (z_q - z); per-block loss partials (validated).
// ---------------------------------------------------------------------------
__global__ __launch_bounds__(256) void vq_gather_kernel(
    const float* __restrict__ z, const float* __restrict__ cb,
    const int* __restrict__ idx, float* __restrict__ zq_out,
    double* __restrict__ partials) {
  const int t = threadIdx.x;
  const size_t g = (size_t)blockIdx.x * 256 + t;
  const int row = (int)(g >> 6);
  const int p   = (int)(g & 63);
  const int k   = idx[row];

  const float4 zv = *reinterpret_cast<const float4*>(&z[g * 4]);
  const float4 ev = *reinterpret_cast<const float4*>(&cb[(size_t)k * DIM + (p << 2)]);

  float4 d4, o;
  d4.x = ev.x - zv.x; d4.y = ev.y - zv.y; d4.z = ev.z - zv.z; d4.w = ev.w - zv.w;
  o.x = zv.x + d4.x;  o.y = zv.y + d4.y;  o.z = zv.z + d4.z;  o.w = zv.w + d4.w;
  *reinterpret_cast<float4*>(&zq_out[g * 4]) = o;

  float s = d4.x * d4.x + d4.y * d4.y + d4.z * d4.z + d4.w * d4.w;
#pragma unroll
  for (int off = 32; off > 0; off >>= 1) s += __shfl_down(s, off);

  __shared__ float wsum[4];
  if ((t & 63) == 0) wsum[t >> 6] = s;
  __syncthreads();
  if (t == 0)
    partials[blockIdx.x] = (double)(wsum[0] + wsum[1] + wsum[2] + wsum[3]);
}

__global__ __launch_bounds__(256) void vq_finalize_kernel(
    const double* __restrict__ partials, float* __restrict__ loss_out) {
  __shared__ double sh[256];
  const int t = threadIdx.x;
  double s = 0.0;
  for (int i = t; i < 8192; i += 256) s += partials[i];
  sh[t] = s;
  __syncthreads();
  for (int stride = 128; stride > 0; stride >>= 1) {
    if (t < stride) sh[t] += sh[t + stride];
    __syncthreads();
  }
  if (t == 0) loss_out[0] = (float)(1.25 * sh[0] / 8388608.0);
}

// ===========================================================================
// Fallback tier (ws too small): r3 pipeline verbatim (validated end-to-end).
// ===========================================================================
__global__ __launch_bounds__(256, 2) void vq_dotmax_f32_kernel(
    const float* __restrict__ A, const float* __restrict__ B,
    float4* __restrict__ records) {
  __shared__ __align__(16) char sA[128 * 128];
  __shared__ __align__(16) char sB[128 * 128];
  __shared__ float4 red2[128][2];

  const int t = threadIdx.x;
  const int l = t & 63, w = t >> 6;
  const int wm = w >> 1, wn = w & 1;
  const int l15 = l & 15, lhi = l >> 4;

  const int b  = blockIdx.x;
  const int wg = (b & 7) * 2048 + (b >> 3);
  const int by = wg >> 6;
  const int bx = wg & 63;
  const long rb    = (long)by * 128;
  const long cbase = (long)bx * 128;

  f32x4 acc[4][4];
#pragma unroll
  for (int i = 0; i < 4; ++i)
#pragma unroll
    for (int j = 0; j < 4; ++j) acc[i][j] = (f32x4)0.0f;

  for (int kc = 0; kc < 4; ++kc) {
#pragma unroll
    for (int p = 0; p < 8; ++p) {
      const int q   = p * 256 + t;
      const int row = q >> 4;
      const int c4  = q & 15;
      const int dst = row * 128 + ((c4 * 8) ^ ((row & 7) << 4));
      const float4 va = *reinterpret_cast<const float4*>(
          &A[(rb + row) * DIM + kc * 64 + c4 * 4]);
      bf16x4v ha;
      ha[0] = (bf16_t)va.x; ha[1] = (bf16_t)va.y;
      ha[2] = (bf16_t)va.z; ha[3] = (bf16_t)va.w;
      *reinterpret_cast<bf16x4v*>(sA + dst) = ha;
      const float4 vb = *reinterpret_cast<const float4*>(
          &B[(cbase + row) * DIM + kc * 64 + c4 * 4]);
      bf16x4v hb;
      hb[0] = (bf16_t)vb.x; hb[1] = (bf16_t)vb.y;
      hb[2] = (bf16_t)vb.z; hb[3] = (bf16_t)vb.w;
      *reinterpret_cast<bf16x4v*>(sB + dst) = hb;
    }
    __syncthreads();
#pragma unroll
    for (int ks = 0; ks < 2; ++ks) {
      bf16x8v a[4], bb[4];
#pragma unroll
      for (int i = 0; i < 4; ++i) {
        const int r = wm * 64 + i * 16 + l15;
        a[i] = *reinterpret_cast<const bf16x8v*>(
            sA + r * 128 + ((ks * 64 + lhi * 16) ^ ((r & 7) << 4)));
        const int cr = wn * 64 + i * 16 + l15;
        bb[i] = *reinterpret_cast<const bf16x8v*>(
            sB + cr * 128 + ((ks * 64 + lhi * 16) ^ ((cr & 7) << 4)));
      }
#pragma unroll
      for (int i = 0; i < 4; ++i)
#pragma unroll
        for (int j = 0; j < 4; ++j)
          acc[i][j] = __builtin_amdgcn_mfma_f32_16x16x32_bf16(a[i], bb[j], acc[i][j], 0, 0, 0);
    }
    __syncthreads();
  }

#pragma unroll
  for (int i = 0; i < 4; ++i) {
#pragma unroll
    for (int r = 0; r < 4; ++r) {
      float v1 = acc[i][0][r];
      int   c1 = (int)cbase + wn * 64 + l15;
      float v2; int c2;
      {
        const float d = acc[i][1][r];
        const int  cc = (int)cbase + wn * 64 + 16 + l15;
        if (d > v1) { v2 = v1; c2 = c1; v1 = d; c1 = cc; }
        else        { v2 = d;  c2 = cc; }
      }
#pragma unroll
      for (int j = 2; j < 4; ++j) {
        const float d = acc[i][j][r];
        const int  cc = (int)cbase + wn * 64 + j * 16 + l15;
        if (d > v1)      { v2 = v1; c2 = c1; v1 = d; c1 = cc; }
        else if (d > v2) { v2 = d;  c2 = cc; }
      }
#pragma unroll
      for (int o = 1; o < 16; o <<= 1) {
        const float b1 = __shfl_xor(v1, o); const int d1 = __shfl_xor(c1, o);
        const float b2 = __shfl_xor(v2, o); const int d2 = __shfl_xor(c2, o);
        if (b1 > v1) {
          const float nv2 = (v1 > b2) ? v1 : b2;
          const int   nc2 = (v1 > b2) ? c1 : d2;
          v2 = nv2; c2 = nc2; v1 = b1; c1 = d1;
        } else if (b1 > v2) { v2 = b1; c2 = d1; }
      }
      if (l15 == 0)
        red2[wm * 64 + i * 16 + lhi * 4 + r][wn] =
            make_float4(v1, __int_as_float(c1), v2, __int_as_float(c2));
    }
  }
  __syncthreads();
  if (t < 128) {
    const float4 A4 = red2[t][0], B4 = red2[t][1];
    float v1 = A4.x, v2 = A4.z;
    int   c1 = __float_as_int(A4.y), c2 = __float_as_int(A4.w);
    top2_merge(v1, c1, v2, c2, B4.x, __float_as_int(B4.y), B4.z, __float_as_int(B4.w));
    records[(size_t)(rb + t) * NGRP + bx] =
        make_float4(v1, __int_as_float(c1), v2, __int_as_float(c2));
  }
}

__global__ __launch_bounds__(256) void vq_select2_kernel(
    const float* __restrict__ z, const float* __restrict__ cb,
    const float4* __restrict__ records, int* __restrict__ idx_out,
    float* __restrict__ idxf_out) {
  __shared__ float sZ[4][DIM];
  const int t = threadIdx.x;
  const int l = t & 63, v = t >> 6;
  const int row = blockIdx.x * 4 + v;

  const float4 rec = records[(size_t)row * NGRP + l];
  const float m1v = rec.x, m2v = rec.z;
  const int   i1  = __float_as_int(rec.y);

  const float4 zv = *reinterpret_cast<const float4*>(&z[(size_t)row * DIM + l * 4]);
  *reinterpret_cast<float4*>(&sZ[v][l * 4]) = zv;

  float M = m1v;
#pragma unroll
  for (int o = 1; o < 64; o <<= 1) M = fmaxf(M, __shfl_xor(M, o));
  const float thr = M - EPS_DOT;
  __syncthreads();

  float S = 0.0f;
  for (int d = 0; d < DIM; ++d) S = fmaf(sZ[v][d], sZ[v][d], S);

  unsigned long long g2 = __ballot(m2v >= thr);
  unsigned long long g1 = __ballot(m1v >= thr) & ~g2;

  float bd = __builtin_inff();
  int   bi = 0x7fffffff;
  unsigned long long mm = g1;
  while (mm) {
    const int g = __builtin_ctzll(mm); mm &= mm - 1;
    const int c = __shfl(i1, g);
    const float* crow = &cb[(size_t)c * DIM];
    float a = 0.0f;
    for (int d = 0; d < DIM; ++d) a = fmaf(sZ[v][d], crow[d], a);
    const float dist = S - 2.0f * a;
    if (dist < bd || (dist == bd && c < bi)) { bd = dist; bi = c; }
  }
  mm = g2;
  while (mm) {
    const int g = __builtin_ctzll(mm); mm &= mm - 1;
#pragma unroll
    for (int half = 0; half < 2; ++half) {
      const int c = g * 128 + half * 64 + l;
      const float* crow = &cb[(size_t)c * DIM];
      float a = 0.0f;
      for (int d = 0; d < DIM; ++d) a = fmaf(sZ[v][d], crow[d], a);
      const float dist = S - 2.0f * a;
      if (dist < bd || (dist == bd && c < bi)) { bd = dist; bi = c; }
    }
  }
#pragma unroll
  for (int o = 1; o < 64; o <<= 1) {
    const float ov = __shfl_xor(bd, o);
    const int   oi = __shfl_xor(bi, o);
    if (ov < bd || (ov == bd && oi < bi)) { bd = ov; bi = oi; }
  }
  if (l == 0) { idx_out[row] = bi; idxf_out[row] = (float)bi; }
}

extern "C" void kernel_launch(void* const* d_in, const int* in_sizes, int n_in,
                              void* d_out, int out_size, void* d_ws, size_t ws_size,
                              hipStream_t stream) {
  const float* z  = (const float*)d_in[0];
  const float* cb = (const float*)d_in[1];
  float* out  = (float*)d_out;
  float* zq   = out;                  // 8388608
  float* loss = out + 8388608;        // 1
  float* idxf = out + 8388609;        // 32768

  // records scratch = exactly the z_q region (32 MB), consumed by select
  // before gather overwrites it (stream-ordered).
  const size_t zb_b  = (size_t)NROWS * DIM * 2;   // 16 MB
  const size_t cbb_b = (size_t)KCB * DIM * 2;     //  4 MB
  const size_t idx_b = (size_t)NROWS * 4;         // 128 KB
  const size_t par_b = 8192 * 8;                  //  64 KB

  if (ws_size >= zb_b + cbb_b + idx_b + par_b) {
    bf16_t* zb   = (bf16_t*)d_ws;
    bf16_t* cbb  = (bf16_t*)((char*)d_ws + zb_b);
    int*    idx  = (int*)((char*)d_ws + zb_b + cbb_b);
    double* partials = (double*)((char*)d_ws + zb_b + cbb_b + idx_b);

    vq_convert_kernel<<<8192, 256, 0, stream>>>(z, zb, NROWS * DIM / 4);
    vq_convert_kernel<<<2048, 256, 0, stream>>>(cb, cbb, KCB * DIM / 4);
    vq_dotmax3_kernel<<<8192, 512, 0, stream>>>(cbb, zb, (uint4*)d_out);
    vq_select3_kernel<<<NROWS / 4, 256, 0, stream>>>(z, cb, (const uint4*)d_out, idx, idxf);
    vq_gather_kernel<<<8192, 256, 0, stream>>>(z, cb, idx, zq, partials);
    vq_finalize_kernel<<<1, 256, 0, stream>>>(partials, loss);
  } else {
    int*    idx      = (int*)d_ws;
    double* partials = (double*)((char*)d_ws + (size_t)NROWS * 4);
    vq_dotmax_f32_kernel<<<16384, 256, 0, stream>>>(z, cb, (float4*)d_out);
    vq_select2_kernel<<<NROWS / 4, 256, 0, stream>>>(z, cb, (const float4*)d_out, idx, idxf);
    vq_gather_kernel<<<8192, 256, 0, stream>>>(z, cb, idx, zq, partials);
    vq_finalize_kernel<<<1, 256, 0, stream>>>(partials, loss);
  }
}

// Round 9
// 428.249 us; speedup vs baseline: 4.3909x; 1.3931x over previous
//
#include <hip/hip_runtime.h>
#include <math.h>

// VectorQuantizer: z (32,256,32,32) f32 -> flat (32768,256); codebook (8192,256) f32.
// d_out (float): [0,8388608) z_q_st ; [8388608] loss ; [8388609,8421377) indices-as-float.
//
// Tier-1: convert z,cb -> bf16; dotmax3 (256x128-tile bf16 MFMA, TOP-3 dot per
// (row, 128-code group) -> records in d_out's z_q region); select4 (LANE-PARALLEL
// exact rescore: each lane one candidate chain, idle lanes compute S, rare
// v3-gated full scans); gather + loss. Rescore arithmetic (sequential fmaf,
// float4-load x,y,z,w order, dist = S - 2*dot, min-then-lowest-code) is
// byte-identical to rounds 1-7 (absmax 0.0 five times).
//
// (Resubmission: round-8 bench died at GPU acquisition, no kernel verdict.)

#define NROWS 32768
#define DIM   256
#define KCB   8192
#define NGRP  64          // 8192 codes / 128 per group
#define EPS_DOT 4e-4f     // prune margin on dot scale (worst-case bf16 err ~5e-5)

typedef __bf16 bf16_t;
typedef bf16_t bf16x4v __attribute__((ext_vector_type(4)));
typedef bf16_t bf16x8v __attribute__((ext_vector_type(8)));
typedef float  f32x4   __attribute__((ext_vector_type(4)));

#ifndef __has_builtin
#define __has_builtin(x) 0
#endif
#if __has_builtin(__builtin_amdgcn_global_load_lds)
#define HAS_GLD_LDS 1
#else
#define HAS_GLD_LDS 0
#endif

// top-3 insert: (v1,c1,v2,c2,v3) <- value w with code d (codes kept for top-2
// only; slot-3 is value-only and triggers a full-group scan when >= thr).
__device__ __forceinline__ void t3_ins(float& v1, unsigned& c1, float& v2,
                                       unsigned& c2, float& v3, float w, unsigned d) {
  if (w > v1)      { v3 = v2; v2 = v1; c2 = c1; v1 = w; c1 = d; }
  else if (w > v2) { v3 = v2; v2 = w;  c2 = d; }
  else if (w > v3) { v3 = w; }
}

__device__ __forceinline__ void top2_merge(float& v1, int& c1, float& v2, int& c2,
                                           float w1, int d1, float w2, int d2) {
  if (w1 > v1 || (w1 == v1 && d1 < c1)) {
    float nv2; int nc2;
    if (v1 > w2 || (v1 == w2 && c1 < d2)) { nv2 = v1; nc2 = c1; }
    else                                   { nv2 = w2; nc2 = d2; }
    v1 = w1; c1 = d1; v2 = nv2; c2 = nc2;
  } else if (w1 > v2 || (w1 == v2 && d1 < c2)) { v2 = w1; c2 = d1; }
}

// ---------------------------------------------------------------------------
// f32 -> bf16 convert.
// ---------------------------------------------------------------------------
__global__ __launch_bounds__(256) void vq_convert_kernel(
    const float* __restrict__ src, bf16_t* __restrict__ dst, int n4) {
  const int i = blockIdx.x * 256 + threadIdx.x;
  if (i < n4) {
    const float4 x = reinterpret_cast<const float4*>(src)[i];
    bf16x4v h;
    h[0] = (bf16_t)x.x; h[1] = (bf16_t)x.y; h[2] = (bf16_t)x.z; h[3] = (bf16_t)x.w;
    reinterpret_cast<bf16x4v*>(dst)[i] = h;
  }
}

// ---------------------------------------------------------------------------
// dotmax3 (unchanged from r7, measured ~240 us): 256 codes (M) x 128 z-rows (N)
// per block, 512 threads, BK=64, single-buffer 2-barrier loop; register-local
// top-3 epilogue. records[row][group] = uint4{v1, v2, v3, (c1<<16)|c2}.
// ---------------------------------------------------------------------------
__global__ __launch_bounds__(512, 4) void vq_dotmax3_kernel(
    const bf16_t* __restrict__ C, const bf16_t* __restrict__ Z,
    uint4* __restrict__ records) {
  __shared__ __align__(16) char sC[256 * 128];   // 32 KB (aliased by red after use)
  __shared__ __align__(16) char sZ[128 * 128];   // 16 KB

  const int t = threadIdx.x;
  const int l = t & 63, w = t >> 6;
  const int wm = w >> 1, wn = w & 1;             // code quarter / z half
  const int l15 = l & 15, lhi = l >> 4;

  const int b  = blockIdx.x;
  const int wg = (b & 7) * 1024 + (b >> 3);      // XCD swizzle (8192 % 8 == 0)
  const int by = wg >> 5;                        // z tile   0..255
  const int bx = wg & 31;                        // code tile 0..31
  const long rb    = (long)by * 128;
  const long cbase = (long)bx * 256;

  const int rl0 = l >> 3;
  const int ch  = (l & 7) ^ rl0;                 // pre-swizzled source chunk

  f32x4 acc[4][4];
#pragma unroll
  for (int i = 0; i < 4; ++i)
#pragma unroll
    for (int j = 0; j < 4; ++j) acc[i][j] = (f32x4)0.0f;

  for (int kc = 0; kc < 4; ++kc) {
    // ---- stage: wave w loads code rows [w*32,w*32+32), z rows [w*16,w*16+16)
#pragma unroll
    for (int p = 0; p < 4; ++p) {
      const bf16_t* gc = C + (cbase + w * 32 + p * 8 + rl0) * 256 + kc * 64 + ch * 8;
      char* lc = sC + (w * 32 + p * 8) * 128;    // wave-uniform base
#if HAS_GLD_LDS
      __builtin_amdgcn_global_load_lds(
          (const __attribute__((address_space(1))) void*)(uintptr_t)gc,
          (__attribute__((address_space(3))) void*)(uint32_t)(uintptr_t)lc,
          16, 0, 0);
#else
      *reinterpret_cast<uint4*>(lc + l * 16) = *reinterpret_cast<const uint4*>(gc);
#endif
    }
#pragma unroll
    for (int p = 0; p < 2; ++p) {
      const bf16_t* gz = Z + (rb + w * 16 + p * 8 + rl0) * 256 + kc * 64 + ch * 8;
      char* lz = sZ + (w * 16 + p * 8) * 128;
#if HAS_GLD_LDS
      __builtin_amdgcn_global_load_lds(
          (const __attribute__((address_space(1))) void*)(uintptr_t)gz,
          (__attribute__((address_space(3))) void*)(uint32_t)(uintptr_t)lz,
          16, 0, 0);
#else
      *reinterpret_cast<uint4*>(lz + l * 16) = *reinterpret_cast<const uint4*>(gz);
#endif
    }
    __syncthreads();
#pragma unroll
    for (int ks = 0; ks < 2; ++ks) {
      bf16x8v a[4], bz[4];
#pragma unroll
      for (int i = 0; i < 4; ++i) {
        const int r  = wm * 64 + i * 16 + l15;   // code row (A operand -> D row)
        a[i]  = *reinterpret_cast<const bf16x8v*>(
            sC + r * 128 + ((ks * 64 + lhi * 16) ^ ((r & 7) << 4)));
        const int rz = wn * 64 + i * 16 + l15;   // z row (B operand -> D col)
        bz[i] = *reinterpret_cast<const bf16x8v*>(
            sZ + rz * 128 + ((ks * 64 + lhi * 16) ^ ((rz & 7) << 4)));
      }
#pragma unroll
      for (int i = 0; i < 4; ++i)
#pragma unroll
        for (int j = 0; j < 4; ++j)
          acc[i][j] = __builtin_amdgcn_mfma_f32_16x16x32_bf16(a[i], bz[j], acc[i][j], 0, 0, 0);
    }
    __syncthreads();                             // protects single buffer + red alias
  }

  // ---- epilogue: D[code][zrow]; in-frag row (lhi*4+reg) = code, col (l15) = z
  uint4* red = reinterpret_cast<uint4*>(sC);     // [128 zloc][4 wm]
  const int code00 = (int)cbase + wm * 64 + lhi * 4;
#pragma unroll
  for (int j = 0; j < 4; ++j) {
    float v1 = -__builtin_inff(), v2 = -__builtin_inff(), v3 = -__builtin_inff();
    unsigned c1 = 0, c2 = 0;
#pragma unroll
    for (int i = 0; i < 4; ++i)
#pragma unroll
      for (int r = 0; r < 4; ++r)
        t3_ins(v1, c1, v2, c2, v3, acc[i][j][r], (unsigned)(code00 + i * 16 + r));
#pragma unroll
    for (int o = 16; o < 64; o <<= 1) {          // merge across lhi groups
      const float    w1 = __shfl_xor(v1, o);
      const unsigned d1 = (unsigned)__shfl_xor((int)c1, o);
      const float    w2 = __shfl_xor(v2, o);
      const unsigned d2 = (unsigned)__shfl_xor((int)c2, o);
      const float    w3 = __shfl_xor(v3, o);
      t3_ins(v1, c1, v2, c2, v3, w1, d1);
      t3_ins(v1, c1, v2, c2, v3, w2, d2);
      if (w3 > v3) v3 = w3;
    }
    if (l < 16) {
      uint4 rec;
      rec.x = __float_as_uint(v1); rec.y = __float_as_uint(v2);
      rec.z = __float_as_uint(v3); rec.w = (c1 << 16) | c2;
      red[(wn * 64 + j * 16 + l15) * 4 + wm] = rec;
    }
  }
  __syncthreads();
  if (t < 256) {                                 // zloc = t&127, group-half g = t>>7
    const int zloc = t & 127, g = t >> 7;
    const uint4 A = red[zloc * 4 + g * 2];
    const uint4 B = red[zloc * 4 + g * 2 + 1];
    float v1 = __uint_as_float(A.x), v2 = __uint_as_float(A.y), v3 = __uint_as_float(A.z);
    unsigned c1 = A.w >> 16, c2 = A.w & 0xffffu;
    t3_ins(v1, c1, v2, c2, v3, __uint_as_float(B.x), B.w >> 16);
    t3_ins(v1, c1, v2, c2, v3, __uint_as_float(B.y), B.w & 0xffffu);
    const float b3 = __uint_as_float(B.z);
    if (b3 > v3) v3 = b3;
    uint4 rec;
    rec.x = __float_as_uint(v1); rec.y = __float_as_uint(v2);
    rec.z = __float_as_uint(v3); rec.w = (c1 << 16) | c2;
    records[(size_t)(rb + zloc) * NGRP + (bx * 2 + g)] = rec;
  }
}

// ---------------------------------------------------------------------------
// select4: per row (1 wave, 4 rows/block). Candidates {c1 of m1, c2 of m2}
// compacted into LDS via ballot-rank; ONE candidate chain PER LANE, idle lanes
// (incl. reserved lane 63) compute S = dot(z,z) with the identical chain.
// S broadcast; dist = S - 2a; min-dist-then-lowest-code. v3-gated full scans
// (rare) after S, lane-parallel as before. Arithmetic byte-identical to r1-r7.
// ---------------------------------------------------------------------------
__global__ __launch_bounds__(256) void vq_select4_kernel(
    const float* __restrict__ z, const float* __restrict__ cb,
    const uint4* __restrict__ records, int* __restrict__ idx_out,
    float* __restrict__ idxf_out) {
  __shared__ float sZf[4][DIM];
  __shared__ unsigned short cand[4][128];
  const int t = threadIdx.x;
  const int l = t & 63, v = t >> 6;
  const int row = blockIdx.x * 4 + v;

  const uint4 rec = records[(size_t)row * NGRP + l];   // 1KB coalesced per row
  const float v1 = __uint_as_float(rec.x);
  const float v2 = __uint_as_float(rec.y);
  const float v3 = __uint_as_float(rec.z);
  const unsigned c1 = rec.w >> 16, c2 = rec.w & 0xffffu;

  const float* zrow = &z[(size_t)row * DIM];
  const float4 zv = *reinterpret_cast<const float4*>(&zrow[l * 4]);
  *reinterpret_cast<float4*>(&sZf[v][l * 4]) = zv;

  float M = v1;
#pragma unroll
  for (int o = 1; o < 64; o <<= 1) M = fmaxf(M, __shfl_xor(M, o));
  const float thr = M - EPS_DOT;

  const unsigned long long m3 = __ballot(v3 >= thr);
  const bool in3 = (m3 >> l) & 1ull;
  const bool i1  = (v1 >= thr) && !in3;
  const bool i2  = (v2 >= thr) && !in3;
  const unsigned long long m1 = __ballot(i1);
  const unsigned long long m2 = __ballot(i2);
  const int n1 = __popcll(m1);
  const int nc = n1 + __popcll(m2);

  const unsigned long long below = (1ull << l) - 1ull;
  if (i1) cand[v][__popcll(m1 & below)]      = (unsigned short)c1;
  if (i2) cand[v][n1 + __popcll(m2 & below)] = (unsigned short)c2;

  __syncthreads();   // publishes sZf and cand (block-wide, uniform)

  float bd = __builtin_inff();
  int   bi = 0x7fffffff;

  // ---- pass 0: lanes 0..62 -> candidates 0..62; lane 63 (and lanes >= nc)
  // compute S = dot(z,z). Same loop, no divergence; exact sequential chain.
  int myc = -1;
  const float* src = zrow;
  if (l < 63 && l < nc) { myc = (int)cand[v][l]; src = &cb[(size_t)myc * DIM]; }
  float a = 0.0f;
  for (int d = 0; d < DIM; d += 4) {
    const float4 q4 = *reinterpret_cast<const float4*>(&sZf[v][d]);
    const float4 s4 = *reinterpret_cast<const float4*>(&src[d]);
    a = fmaf(q4.x, s4.x, a); a = fmaf(q4.y, s4.y, a);
    a = fmaf(q4.z, s4.z, a); a = fmaf(q4.w, s4.w, a);
  }
  const float S = __shfl(a, 63);       // lane 63 always computed S
  if (myc >= 0) {
    const float dist = S - 2.0f * a;
    if (dist < bd || (dist == bd && myc < bi)) { bd = dist; bi = myc; }
  }

  // ---- overflow passes (nc > 63; essentially never)
  for (int base = 63; base < nc; base += 64) {
    const int ci = base + l;
    if (ci < nc) {
      const int c = (int)cand[v][ci];
      const float* crow = &cb[(size_t)c * DIM];
      float aa = 0.0f;
      for (int d = 0; d < DIM; d += 4) {
        const float4 q4 = *reinterpret_cast<const float4*>(&sZf[v][d]);
        const float4 s4 = *reinterpret_cast<const float4*>(&crow[d]);
        aa = fmaf(q4.x, s4.x, aa); aa = fmaf(q4.y, s4.y, aa);
        aa = fmaf(q4.z, s4.z, aa); aa = fmaf(q4.w, s4.w, aa);
      }
      const float dist = S - 2.0f * aa;
      if (dist < bd || (dist == bd && c < bi)) { bd = dist; bi = c; }
    }
  }

  // ---- rare: full 128-code scan of v3-qualifying groups (lane-parallel)
  unsigned long long mm = m3;
  while (mm) {
    const int g = __builtin_ctzll(mm); mm &= mm - 1;
#pragma unroll
    for (int half = 0; half < 2; ++half) {
      const int c = g * 128 + half * 64 + l;
      const float* crow = &cb[(size_t)c * DIM];
      float aa = 0.0f;
      for (int d = 0; d < DIM; d += 4) {
        const float4 q4 = *reinterpret_cast<const float4*>(&sZf[v][d]);
        const float4 s4 = *reinterpret_cast<const float4*>(&crow[d]);
        aa = fmaf(q4.x, s4.x, aa); aa = fmaf(q4.y, s4.y, aa);
        aa = fmaf(q4.z, s4.z, aa); aa = fmaf(q4.w, s4.w, aa);
      }
      const float dist = S - 2.0f * aa;
      if (dist < bd || (dist == bd && c < bi)) { bd = dist; bi = c; }
    }
  }

#pragma unroll
  for (int o = 1; o < 64; o <<= 1) {
    const float ov = __shfl_xor(bd, o);
    const int   oi = __shfl_xor(bi, o);
    if (ov < bd || (ov == bd && oi < bi)) { bd = ov; bi = oi; }
  }
  if (l == 0) { idx_out[row] = bi; idxf_out[row] = (float)bi; }
}

// ---------------------------------------------------------------------------
// Gather z_q, z_q_st = z + (z_q - z); per-block loss partials (validated).
// ---------------------------------------------------------------------------
__global__ __launch_bounds__(256) void vq_gather_kernel(
    const float* __restrict__ z, const float* __restrict__ cb,
    const int* __restrict__ idx, float* __restrict__ zq_out,
    double* __restrict__ partials) {
  const int t = threadIdx.x;
  const size_t g = (size_t)blockIdx.x * 256 + t;
  const int row = (int)(g >> 6);
  const int p   = (int)(g & 63);
  const int k   = idx[row];

  const float4 zv = *reinterpret_cast<const float4*>(&z[g * 4]);
  const float4 ev = *reinterpret_cast<const float4*>(&cb[(size_t)k * DIM + (p << 2)]);

  float4 d4, o;
  d4.x = ev.x - zv.x; d4.y = ev.y - zv.y; d4.z = ev.z - zv.z; d4.w = ev.w - zv.w;
  o.x = zv.x + d4.x;  o.y = zv.y + d4.y;  o.z = zv.z + d4.z;  o.w = zv.w + d4.w;
  *reinterpret_cast<float4*>(&zq_out[g * 4]) = o;

  float s = d4.x * d4.x + d4.y * d4.y + d4.z * d4.z + d4.w * d4.w;
#pragma unroll
  for (int off = 32; off > 0; off >>= 1) s += __shfl_down(s, off);

  __shared__ float wsum[4];
  if ((t & 63) == 0) wsum[t >> 6] = s;
  __syncthreads();
  if (t == 0)
    partials[blockIdx.x] = (double)(wsum[0] + wsum[1] + wsum[2] + wsum[3]);
}

__global__ __launch_bounds__(256) void vq_finalize_kernel(
    const double* __restrict__ partials, float* __restrict__ loss_out) {
  __shared__ double sh[256];
  const int t = threadIdx.x;
  double s = 0.0;
  for (int i = t; i < 8192; i += 256) s += partials[i];
  sh[t] = s;
  __syncthreads();
  for (int stride = 128; stride > 0; stride >>= 1) {
    if (t < stride) sh[t] += sh[t + stride];
    __syncthreads();
  }
  if (t == 0) loss_out[0] = (float)(1.25 * sh[0] / 8388608.0);
}

// ===========================================================================
// Fallback tier (ws too small): r3 pipeline verbatim (validated end-to-end).
// ===========================================================================
__global__ __launch_bounds__(256, 2) void vq_dotmax_f32_kernel(
    const float* __restrict__ A, const float* __restrict__ B,
    float4* __restrict__ records) {
  __shared__ __align__(16) char sA[128 * 128];
  __shared__ __align__(16) char sB[128 * 128];
  __shared__ float4 red2[128][2];

  const int t = threadIdx.x;
  const int l = t & 63, w = t >> 6;
  const int wm = w >> 1, wn = w & 1;
  const int l15 = l & 15, lhi = l >> 4;

  const int b  = blockIdx.x;
  const int wg = (b & 7) * 2048 + (b >> 3);
  const int by = wg >> 6;
  const int bx = wg & 63;
  const long rb    = (long)by * 128;
  const long cbase = (long)bx * 128;

  f32x4 acc[4][4];
#pragma unroll
  for (int i = 0; i < 4; ++i)
#pragma unroll
    for (int j = 0; j < 4; ++j) acc[i][j] = (f32x4)0.0f;

  for (int kc = 0; kc < 4; ++kc) {
#pragma unroll
    for (int p = 0; p < 8; ++p) {
      const int q   = p * 256 + t;
      const int row = q >> 4;
      const int c4  = q & 15;
      const int dst = row * 128 + ((c4 * 8) ^ ((row & 7) << 4));
      const float4 va = *reinterpret_cast<const float4*>(
          &A[(rb + row) * DIM + kc * 64 + c4 * 4]);
      bf16x4v ha;
      ha[0] = (bf16_t)va.x; ha[1] = (bf16_t)va.y;
      ha[2] = (bf16_t)va.z; ha[3] = (bf16_t)va.w;
      *reinterpret_cast<bf16x4v*>(sA + dst) = ha;
      const float4 vb = *reinterpret_cast<const float4*>(
          &B[(cbase + row) * DIM + kc * 64 + c4 * 4]);
      bf16x4v hb;
      hb[0] = (bf16_t)vb.x; hb[1] = (bf16_t)vb.y;
      hb[2] = (bf16_t)vb.z; hb[3] = (bf16_t)vb.w;
      *reinterpret_cast<bf16x4v*>(sB + dst) = hb;
    }
    __syncthreads();
#pragma unroll
    for (int ks = 0; ks < 2; ++ks) {
      bf16x8v a[4], bb[4];
#pragma unroll
      for (int i = 0; i < 4; ++i) {
        const int r = wm * 64 + i * 16 + l15;
        a[i] = *reinterpret_cast<const bf16x8v*>(
            sA + r * 128 + ((ks * 64 + lhi * 16) ^ ((r & 7) << 4)));
        const int cr = wn * 64 + i * 16 + l15;
        bb[i] = *reinterpret_cast<const bf16x8v*>(
            sB + cr * 128 + ((ks * 64 + lhi * 16) ^ ((cr & 7) << 4)));
      }
#pragma unroll
      for (int i = 0; i < 4; ++i)
#pragma unroll
        for (int j = 0; j < 4; ++j)
          acc[i][j] = __builtin_amdgcn_mfma_f32_16x16x32_bf16(a[i], bb[j], acc[i][j], 0, 0, 0);
    }
    __syncthreads();
  }

#pragma unroll
  for (int i = 0; i < 4; ++i) {
#pragma unroll
    for (int r = 0; r < 4; ++r) {
      float v1 = acc[i][0][r];
      int   c1 = (int)cbase + wn * 64 + l15;
      float v2; int c2;
      {
        const float d = acc[i][1][r];
        const int  cc = (int)cbase + wn * 64 + 16 + l15;
        if (d > v1) { v2 = v1; c2 = c1; v1 = d; c1 = cc; }
        else        { v2 = d;  c2 = cc; }
      }
#pragma unroll
      for (int j = 2; j < 4; ++j) {
        const float d = acc[i][j][r];
        const int  cc = (int)cbase + wn * 64 + j * 16 + l15;
        if (d > v1)      { v2 = v1; c2 = c1; v1 = d; c1 = cc; }
        else if (d > v2) { v2 = d;  c2 = cc; }
      }
#pragma unroll
      for (int o = 1; o < 16; o <<= 1) {
        const float b1 = __shfl_xor(v1, o); const int d1 = __shfl_xor(c1, o);
        const float b2 = __shfl_xor(v2, o); const int d2 = __shfl_xor(c2, o);
        if (b1 > v1) {
          const float nv2 = (v1 > b2) ? v1 : b2;
          const int   nc2 = (v1 > b2) ? c1 : d2;
          v2 = nv2; c2 = nc2; v1 = b1; c1 = d1;
        } else if (b1 > v2) { v2 = b1; c2 = d1; }
      }
      if (l15 == 0)
        red2[wm * 64 + i * 16 + lhi * 4 + r][wn] =
            make_float4(v1, __int_as_float(c1), v2, __int_as_float(c2));
    }
  }
  __syncthreads();
  if (t < 128) {
    const float4 A4 = red2[t][0], B4 = red2[t][1];
    float v1 = A4.x, v2 = A4.z;
    int   c1 = __float_as_int(A4.y), c2 = __float_as_int(A4.w);
    top2_merge(v1, c1, v2, c2, B4.x, __float_as_int(B4.y), B4.z, __float_as_int(B4.w));
    records[(size_t)(rb + t) * NGRP + bx] =
        make_float4(v1, __int_as_float(c1), v2, __int_as_float(c2));
  }
}

__global__ __launch_bounds__(256) void vq_select2_kernel(
    const float* __restrict__ z, const float* __restrict__ cb,
    const float4* __restrict__ records, int* __restrict__ idx_out,
    float* __restrict__ idxf_out) {
  __shared__ float sZ[4][DIM];
  const int t = threadIdx.x;
  const int l = t & 63, v = t >> 6;
  const int row = blockIdx.x * 4 + v;

  const float4 rec = records[(size_t)row * NGRP + l];
  const float m1v = rec.x, m2v = rec.z;
  const int   i1  = __float_as_int(rec.y);

  const float4 zv = *reinterpret_cast<const float4*>(&z[(size_t)row * DIM + l * 4]);
  *reinterpret_cast<float4*>(&sZ[v][l * 4]) = zv;

  float M = m1v;
#pragma unroll
  for (int o = 1; o < 64; o <<= 1) M = fmaxf(M, __shfl_xor(M, o));
  const float thr = M - EPS_DOT;
  __syncthreads();

  float S = 0.0f;
  for (int d = 0; d < DIM; ++d) S = fmaf(sZ[v][d], sZ[v][d], S);

  unsigned long long g2 = __ballot(m2v >= thr);
  unsigned long long g1 = __ballot(m1v >= thr) & ~g2;

  float bd = __builtin_inff();
  int   bi = 0x7fffffff;
  unsigned long long mm = g1;
  while (mm) {
    const int g = __builtin_ctzll(mm); mm &= mm - 1;
    const int c = __shfl(i1, g);
    const float* crow = &cb[(size_t)c * DIM];
    float a = 0.0f;
    for (int d = 0; d < DIM; ++d) a = fmaf(sZ[v][d], crow[d], a);
    const float dist = S - 2.0f * a;
    if (dist < bd || (dist == bd && c < bi)) { bd = dist; bi = c; }
  }
  mm = g2;
  while (mm) {
    const int g = __builtin_ctzll(mm); mm &= mm - 1;
#pragma unroll
    for (int half = 0; half < 2; ++half) {
      const int c = g * 128 + half * 64 + l;
      const float* crow = &cb[(size_t)c * DIM];
      float a = 0.0f;
      for (int d = 0; d < DIM; ++d) a = fmaf(sZ[v][d], crow[d], a);
      const float dist = S - 2.0f * a;
      if (dist < bd || (dist == bd && c < bi)) { bd = dist; bi = c; }
    }
  }
#pragma unroll
  for (int o = 1; o < 64; o <<= 1) {
    const float ov = __shfl_xor(bd, o);
    const int   oi = __shfl_xor(bi, o);
    if (ov < bd || (ov == bd && oi < bi)) { bd = ov; bi = oi; }
  }
  if (l == 0) { idx_out[row] = bi; idxf_out[row] = (float)bi; }
}

extern "C" void kernel_launch(void* const* d_in, const int* in_sizes, int n_in,
                              void* d_out, int out_size, void* d_ws, size_t ws_size,
                              hipStream_t stream) {
  const float* z  = (const float*)d_in[0];
  const float* cb = (const float*)d_in[1];
  float* out  = (float*)d_out;
  float* zq   = out;                  // 8388608
  float* loss = out + 8388608;        // 1
  float* idxf = out + 8388609;        // 32768

  // records scratch = exactly the z_q region (32 MB), consumed by select
  // before gather overwrites it (stream-ordered).
  const size_t zb_b  = (size_t)NROWS * DIM * 2;   // 16 MB
  const size_t cbb_b = (size_t)KCB * DIM * 2;     //  4 MB
  const size_t idx_b = (size_t)NROWS * 4;         // 128 KB
  const size_t par_b = 8192 * 8;                  //  64 KB

  if (ws_size >= zb_b + cbb_b + idx_b + par_b) {
    bf16_t* zb   = (bf16_t*)d_ws;
    bf16_t* cbb  = (bf16_t*)((char*)d_ws + zb_b);
    int*    idx  = (int*)((char*)d_ws + zb_b + cbb_b);
    double* partials = (double*)((char*)d_ws + zb_b + cbb_b + idx_b);

    vq_convert_kernel<<<8192, 256, 0, stream>>>(z, zb, NROWS * DIM / 4);
    vq_convert_kernel<<<2048, 256, 0, stream>>>(cb, cbb, KCB * DIM / 4);
    vq_dotmax3_kernel<<<8192, 512, 0, stream>>>(cbb, zb, (uint4*)d_out);
    vq_select4_kernel<<<NROWS / 4, 256, 0, stream>>>(z, cb, (const uint4*)d_out, idx, idxf);
    vq_gather_kernel<<<8192, 256, 0, stream>>>(z, cb, idx, zq, partials);
    vq_finalize_kernel<<<1, 256, 0, stream>>>(partials, loss);
  } else {
    int*    idx      = (int*)d_ws;
    double* partials = (double*)((char*)d_ws + (size_t)NROWS * 4);
    vq_dotmax_f32_kernel<<<16384, 256, 0, stream>>>(z, cb, (float4*)d_out);
    vq_select2_kernel<<<NROWS / 4, 256, 0, stream>>>(z, cb, (const float4*)d_out, idx, idxf);
    vq_gather_kernel<<<8192, 256, 0, stream>>>(z, cb, idx, zq, partials);
    vq_finalize_kernel<<<1, 256, 0, stream>>>(partials, loss);
  }
}